// Round 1
// baseline (1061.179 us; speedup 1.0000x reference)
//
#include <hip/hip_runtime.h>
#include <math.h>

#define N 1024
#define F 4096
#define NLAYERS 24
#define VOCAB 50277

__device__ __forceinline__ float wred(float v) {
#pragma unroll
  for (int o = 32; o > 0; o >>= 1) v += __shfl_down(v, o, 64);
  return v;
}

// LayerNorm of a 1024-vector distributed as one float4 per thread (256 threads).
// Returns the normalized float4; uses s_red[8] LDS scratch.
__device__ __forceinline__ float4 block_ln4(float4 xv, const float* w, const float* b,
                                            float* s_red) {
  int tid = threadIdx.x;
  float s = xv.x + xv.y + xv.z + xv.w;
  float sq = xv.x * xv.x + xv.y * xv.y + xv.z * xv.z + xv.w * xv.w;
#pragma unroll
  for (int o = 32; o > 0; o >>= 1) {
    s += __shfl_down(s, o, 64);
    sq += __shfl_down(sq, o, 64);
  }
  int wid = tid >> 6;
  if ((tid & 63) == 0) { s_red[wid] = s; s_red[4 + wid] = sq; }
  __syncthreads();
  if (tid == 0) {
    float ts = s_red[0] + s_red[1] + s_red[2] + s_red[3];
    float tq = s_red[4] + s_red[5] + s_red[6] + s_red[7];
    float mu = ts * (1.0f / N);
    float var = tq * (1.0f / N) - mu * mu;
    s_red[0] = mu;
    s_red[1] = rsqrtf(var + 1e-5f);
  }
  __syncthreads();
  float mu = s_red[0], rstd = s_red[1];
  const float4 wv = ((const float4*)w)[tid];
  const float4 bv = ((const float4*)b)[tid];
  float4 y;
  y.x = (xv.x - mu) * rstd * wv.x + bv.x;
  y.y = (xv.y - mu) * rstd * wv.y + bv.y;
  y.z = (xv.z - mu) * rstd * wv.z + bv.z;
  y.w = (xv.w - mu) * rstd * wv.w + bv.w;
  return y;
}

__device__ __forceinline__ float4 mix4(float4 a, float4 s, float4 m) {
  float4 r;
  r.x = a.x * m.x + s.x * (1.f - m.x);
  r.y = a.y * m.y + s.y * (1.f - m.y);
  r.z = a.z * m.z + s.z * (1.f - m.z);
  r.w = a.w * m.w + s.w * (1.f - m.w);
  return r;
}

// one wave computes dot(wrow[0:len], s_vec[0:len]); len multiple of 256
__device__ __forceinline__ float wave_dot(const float* __restrict__ wrow,
                                          const float* __restrict__ s_vec,
                                          int len, int lane) {
  float acc = 0.f;
  for (int c = lane * 4; c < len; c += 256) {
    float4 wv = *(const float4*)(wrow + c);
    float4 vv = *(const float4*)(s_vec + c);
    acc = fmaf(wv.x, vv.x, acc);
    acc = fmaf(wv.y, vv.y, acc);
    acc = fmaf(wv.z, vv.z, acc);
    acc = fmaf(wv.w, vv.w, acc);
  }
  return wred(acc);
}

__device__ __forceinline__ float sigmoidf(float x) { return 1.f / (1.f + expf(-x)); }

__global__ __launch_bounds__(256) void k_embed(const int* __restrict__ ctx,
                                               const float* __restrict__ emb,
                                               const float* __restrict__ ln0w,
                                               const float* __restrict__ ln0b,
                                               float* __restrict__ x_out) {
  __shared__ float s_red[8];
  int tid = threadIdx.x;
  int t_last = ctx[1], t_prev = ctx[0];
  float4 e1 = ((const float4*)(emb + (size_t)t_last * N))[tid];
  float4 e0 = ((const float4*)(emb + (size_t)t_prev * N))[tid];
  float4 xv;
  xv.x = (e1.x * 4.f + e0.x) * 0.2f;
  xv.y = (e1.y * 4.f + e0.y) * 0.2f;
  xv.z = (e1.z * 4.f + e0.z) * 0.2f;
  xv.w = (e1.w * 4.f + e0.w) * 0.2f;
  float4 y = block_ln4(xv, ln0w, ln0b, s_red);
  ((float4*)x_out)[tid] = y;
}

// xl = LN(x); xk/xv/xr = mix(xl, s1); k = kw@xk, v = vw@xv, r = sigmoid(rw@xr)
__global__ __launch_bounds__(256) void k_kvr(
    const float* __restrict__ x, const float* __restrict__ s1,
    const float* __restrict__ ln1w, const float* __restrict__ ln1b,
    const float* __restrict__ amk, const float* __restrict__ amv,
    const float* __restrict__ amr, const float* __restrict__ kw,
    const float* __restrict__ vw, const float* __restrict__ rw,
    float* __restrict__ k_out, float* __restrict__ v_out,
    float* __restrict__ r_out, float* __restrict__ xl_out) {
  __shared__ float s_xk[N], s_xv[N], s_xr[N];
  __shared__ float s_red[8];
  int tid = threadIdx.x;
  float4 xv = ((const float4*)x)[tid];
  float4 xl = block_ln4(xv, ln1w, ln1b, s_red);
  if (blockIdx.x == 0) ((float4*)xl_out)[tid] = xl;
  float4 sv = ((const float4*)s1)[tid];
  ((float4*)s_xk)[tid] = mix4(xl, sv, ((const float4*)amk)[tid]);
  ((float4*)s_xv)[tid] = mix4(xl, sv, ((const float4*)amv)[tid]);
  ((float4*)s_xr)[tid] = mix4(xl, sv, ((const float4*)amr)[tid]);
  __syncthreads();
  int lane = tid & 63;
  int gw = (blockIdx.x << 2) + (tid >> 6);
  int nw = gridDim.x << 2;
  for (int row = gw; row < 3 * N; row += nw) {
    int m = row >> 10;
    int rr = row & (N - 1);
    const float* wrow =
        (m == 0 ? kw : (m == 1 ? vw : rw)) + (size_t)rr * N;
    const float* vec = (m == 0 ? s_xk : (m == 1 ? s_xv : s_xr));
    float acc = wave_dot(wrow, vec, N, lane);
    if (lane == 0) {
      if (m == 0) k_out[rr] = acc;
      else if (m == 1) v_out[rr] = acc;
      else r_out[rr] = sigmoidf(acc);
    }
  }
}

__device__ __forceinline__ void wkv1(float k, float v, float r, float aa, float bb,
                                     float pp, float tf, float td, float& rab,
                                     float& naa, float& nbb, float& npp) {
  float ww = tf + k;
  float q = fmaxf(pp, ww);
  float e1 = expf(pp - q);
  float e2 = expf(ww - q);
  float a = e1 * aa + e2 * v;
  float b = e1 * bb + e2;
  rab = r * a / b;
  float ww2 = pp + td;
  float q2 = fmaxf(ww2, k);
  float f1 = expf(ww2 - q2);
  float f2 = expf(k - q2);
  naa = f1 * aa + f2 * v;
  nbb = f1 * bb + f2;
  npp = q2;
}

// WKV recurrence (redundant per block) + sx = x + ow @ (r*a/b); writes new aa/bb/pp
__global__ __launch_bounds__(256) void k_ow(
    const float* __restrict__ x, const float* __restrict__ kx,
    const float* __restrict__ vx, const float* __restrict__ rx,
    const float* __restrict__ aa_s, const float* __restrict__ bb_s,
    const float* __restrict__ pp_s, const float* __restrict__ tf,
    const float* __restrict__ td, const float* __restrict__ ow,
    float* __restrict__ sx_out, float* __restrict__ naa_out,
    float* __restrict__ nbb_out, float* __restrict__ npp_out) {
  __shared__ float s_rab[N];
  int tid = threadIdx.x;
  float4 k4 = ((const float4*)kx)[tid];
  float4 v4 = ((const float4*)vx)[tid];
  float4 r4 = ((const float4*)rx)[tid];
  float4 aa4 = ((const float4*)aa_s)[tid];
  float4 bb4 = ((const float4*)bb_s)[tid];
  float4 pp4 = ((const float4*)pp_s)[tid];
  float4 tf4 = ((const float4*)tf)[tid];
  float4 td4 = ((const float4*)td)[tid];
  float4 rab4, naa4, nbb4, npp4;
  wkv1(k4.x, v4.x, r4.x, aa4.x, bb4.x, pp4.x, tf4.x, td4.x, rab4.x, naa4.x, nbb4.x, npp4.x);
  wkv1(k4.y, v4.y, r4.y, aa4.y, bb4.y, pp4.y, tf4.y, td4.y, rab4.y, naa4.y, nbb4.y, npp4.y);
  wkv1(k4.z, v4.z, r4.z, aa4.z, bb4.z, pp4.z, tf4.z, td4.z, rab4.z, naa4.z, nbb4.z, npp4.z);
  wkv1(k4.w, v4.w, r4.w, aa4.w, bb4.w, pp4.w, tf4.w, td4.w, rab4.w, naa4.w, nbb4.w, npp4.w);
  ((float4*)s_rab)[tid] = rab4;
  if (blockIdx.x == 0) {
    ((float4*)naa_out)[tid] = naa4;
    ((float4*)nbb_out)[tid] = nbb4;
    ((float4*)npp_out)[tid] = npp4;
  }
  __syncthreads();
  int lane = tid & 63;
  int gw = (blockIdx.x << 2) + (tid >> 6);
  int nw = gridDim.x << 2;
  for (int row = gw; row < N; row += nw) {
    float acc = wave_dot(ow + (size_t)row * N, s_rab, N, lane);
    if (lane == 0) sx_out[row] = x[row] + acc;
  }
}

// x2 = LN(sx); fxk/fxr = mix(x2, s0); kk = relu(fkw@fxk)^2 ; r2 = sigmoid(frw@fxr)
__global__ __launch_bounds__(256) void k_ffn1(
    const float* __restrict__ sx, const float* __restrict__ s0,
    const float* __restrict__ ln2w, const float* __restrict__ ln2b,
    const float* __restrict__ fmk, const float* __restrict__ fmr,
    const float* __restrict__ fkw, const float* __restrict__ frw,
    float* __restrict__ kk_out, float* __restrict__ r2_out,
    float* __restrict__ x2_out) {
  __shared__ float s_fxk[N], s_fxr[N];
  __shared__ float s_red[8];
  int tid = threadIdx.x;
  float4 sxv = ((const float4*)sx)[tid];
  float4 x2 = block_ln4(sxv, ln2w, ln2b, s_red);
  if (blockIdx.x == 0) ((float4*)x2_out)[tid] = x2;
  float4 s0v = ((const float4*)s0)[tid];
  ((float4*)s_fxk)[tid] = mix4(x2, s0v, ((const float4*)fmk)[tid]);
  ((float4*)s_fxr)[tid] = mix4(x2, s0v, ((const float4*)fmr)[tid]);
  __syncthreads();
  int lane = tid & 63;
  int gw = (blockIdx.x << 2) + (tid >> 6);
  int nw = gridDim.x << 2;
  for (int row = gw; row < F + N; row += nw) {
    if (row < F) {
      float acc = wave_dot(fkw + (size_t)row * N, s_fxk, N, lane);
      if (lane == 0) {
        float t = fmaxf(acc, 0.f);
        kk_out[row] = t * t;
      }
    } else {
      int rr = row - F;
      float acc = wave_dot(frw + (size_t)rr * N, s_fxr, N, lane);
      if (lane == 0) r2_out[rr] = sigmoidf(acc);
    }
  }
}

// out = sx + r2 * (fvw @ kk)
__global__ __launch_bounds__(256) void k_ffn2(
    const float* __restrict__ sx, const float* __restrict__ kk,
    const float* __restrict__ r2, const float* __restrict__ fvw,
    float* __restrict__ x_out) {
  __shared__ float s_kk[F];
  int tid = threadIdx.x;
#pragma unroll
  for (int i = 0; i < 4; i++)
    ((float4*)s_kk)[i * 256 + tid] = ((const float4*)kk)[i * 256 + tid];
  __syncthreads();
  int lane = tid & 63;
  int gw = (blockIdx.x << 2) + (tid >> 6);
  int nw = gridDim.x << 2;
  for (int row = gw; row < N; row += nw) {
    float acc = wave_dot(fvw + (size_t)row * F, s_kk, F, lane);
    if (lane == 0) x_out[row] = sx[row] + r2[row] * acc;
  }
}

__global__ __launch_bounds__(256) void k_head(
    const float* __restrict__ x, const float* __restrict__ lnw,
    const float* __restrict__ lnb, const float* __restrict__ head,
    float* __restrict__ logits) {
  __shared__ float s_xf[N];
  __shared__ float s_red[8];
  int tid = threadIdx.x;
  float4 xv = ((const float4*)x)[tid];
  float4 y = block_ln4(xv, lnw, lnb, s_red);
  ((float4*)s_xf)[tid] = y;
  __syncthreads();
  int lane = tid & 63;
  int gw = (blockIdx.x << 2) + (tid >> 6);
  int nw = gridDim.x << 2;
  for (int row = gw; row < VOCAB; row += nw) {
    float acc = wave_dot(head + (size_t)row * N, s_xf, N, lane);
    if (lane == 0) logits[row] = acc;
  }
}

extern "C" void kernel_launch(void* const* d_in, const int* in_sizes, int n_in,
                              void* d_out, int out_size, void* d_ws, size_t ws_size,
                              hipStream_t stream) {
  const int* ctx = (const int*)d_in[0];
  const float* state = (const float*)d_in[1];
  const float* emb = (const float*)d_in[2];
  const float* ln0w = (const float*)d_in[3];
  const float* ln0b = (const float*)d_in[4];
  const float* ln1w = (const float*)d_in[5];
  const float* ln1b = (const float*)d_in[6];
  const float* amk = (const float*)d_in[7];
  const float* amv = (const float*)d_in[8];
  const float* amr = (const float*)d_in[9];
  const float* tf = (const float*)d_in[10];
  const float* td = (const float*)d_in[11];
  const float* kw = (const float*)d_in[12];
  const float* vw = (const float*)d_in[13];
  const float* rw = (const float*)d_in[14];
  const float* ow = (const float*)d_in[15];
  const float* ln2w = (const float*)d_in[16];
  const float* ln2b = (const float*)d_in[17];
  const float* fmk = (const float*)d_in[18];
  const float* fmr = (const float*)d_in[19];
  const float* fkw = (const float*)d_in[20];
  const float* fvw = (const float*)d_in[21];
  const float* frw = (const float*)d_in[22];
  const float* lnoutw = (const float*)d_in[23];
  const float* lnoutb = (const float*)d_in[24];
  const float* head = (const float*)d_in[25];

  float* out = (float*)d_out;
  float* logits = out;
  float* st_out = out + VOCAB;

  float* ws = (float*)d_ws;
  float* x = ws;                 // N
  float* kbuf = ws + N;          // N
  float* vbuf = ws + 2 * N;      // N
  float* rbuf = ws + 3 * N;      // N
  float* sxbuf = ws + 4 * N;     // N
  float* kkbuf = ws + 5 * N;     // F
  float* r2buf = ws + 5 * N + F; // N

  k_embed<<<1, 256, 0, stream>>>(ctx, emb, ln0w, ln0b, x);

  for (int l = 0; l < NLAYERS; ++l) {
    const size_t nn = (size_t)N * N;
    const float* st_l = state + (size_t)l * 5 * N;
    float* sto = st_out + (size_t)l * 5 * N;
    k_kvr<<<256, 256, 0, stream>>>(x, st_l + N, ln1w + l * N, ln1b + l * N,
                                   amk + l * N, amv + l * N, amr + l * N,
                                   kw + l * nn, vw + l * nn, rw + l * nn,
                                   kbuf, vbuf, rbuf, sto + N);
    k_ow<<<256, 256, 0, stream>>>(x, kbuf, vbuf, rbuf, st_l + 2 * N,
                                  st_l + 3 * N, st_l + 4 * N, tf + l * N,
                                  td + l * N, ow + l * nn, sxbuf, sto + 2 * N,
                                  sto + 3 * N, sto + 4 * N);
    k_ffn1<<<256, 256, 0, stream>>>(sxbuf, st_l, ln2w + l * N, ln2b + l * N,
                                    fmk + l * N, fmr + l * N,
                                    fkw + (size_t)l * F * N, frw + l * nn,
                                    kkbuf, r2buf, sto);
    k_ffn2<<<256, 256, 0, stream>>>(sxbuf, kkbuf, r2buf,
                                    fvw + (size_t)l * N * F, x);
  }

  k_head<<<512, 256, 0, stream>>>(x, lnoutw, lnoutb, head, logits);
}